// Round 6
// baseline (163.501 us; speedup 1.0000x reference)
//
#include <hip/hip_runtime.h>
#include <hip/hip_bf16.h>
#include <math.h>

#define N_RAYS   32768
#define N_SAMP   1048576
#define HID      64
#define ITERS    4
#define BLK_A    1024   // 1024 blk * 4 waves * ITERS * 64 = 1,048,576 samples

typedef short bf8 __attribute__((ext_vector_type(8)));   // 8 x bf16 bits
typedef float f4  __attribute__((ext_vector_type(4)));

union BF8U { bf8 v; unsigned u[4]; };

// Branch-free RNE f32->bf16 pair-pack. Identical result to the C++ (__bf16)
// cast for finite inputs, but ~6 VALU ops instead of ~14 (the cast's lowered
// form carries NaN handling; our MFMA outputs are always finite).
// R5 evidence: VALUBusy 55% at ~2490 VALU-inst/iter, ~85% of it bf16 packing.
static __device__ __forceinline__ unsigned pk2(float a, float b) {
#if __has_builtin(__builtin_amdgcn_cvt_pk_bf16_f32)
    typedef __bf16 bf16x2 __attribute__((ext_vector_type(2)));
    bf16x2 t = __builtin_amdgcn_cvt_pk_bf16_f32(a, b);
    return __builtin_bit_cast(unsigned, t);
#else
    unsigned ua = __builtin_bit_cast(unsigned, a);
    unsigned ub = __builtin_bit_cast(unsigned, b);
    ua += 0x7fffu + ((ua >> 16) & 1u);     // RNE round into high half
    ub += 0x7fffu + ((ub >> 16) & 1u);
    return (ua >> 16) | (ub & 0xFFFF0000u);  // low16 = bf16(a), high16 = bf16(b)
#endif
}
static __device__ __forceinline__ unsigned pk2r(float a, float b) {
    return pk2(fmaxf(a, 0.f), fmaxf(b, 0.f));
}
static __device__ __forceinline__ f4 mfma16(bf8 a, bf8 b, f4 c) {
    return __builtin_amdgcn_mfma_f32_16x16x32_bf16(a, b, c, 0, 0, 0);
}

// ---------------------------------------------------------------------------
// Pass A: 64 samples per wave-iteration, 4 16-col MFMA tiles.
// Tile-select trick on B1 (tile u nonzero only in quad u -> each lane feeds
// its OWN sample). L3 uses ROW-DUPLICATED A3 (rows 4q+rr = sigma,r,g,b for
// every q) so lane(q,n)'s C-regs of tile u==q are its own sample's outputs:
// no exec masks, no dt shuffle, one full-width epilogue + coalesced store.
// NOTE: __launch_bounds__(256,2) — (256,4) caps unified VGPR+AGPR at 128 and
// causes catastrophic scratch spill (R4: FETCH 7MB->852MB, 64us->313us).
// ---------------------------------------------------------------------------
__global__ __launch_bounds__(256, 2) void pass_a(
    const float* __restrict__ rays_o, const float* __restrict__ rays_d,
    const float* __restrict__ t_starts, const float* __restrict__ t_ends,
    const int*   __restrict__ ray_idx,
    const float* __restrict__ Wd1, const float* __restrict__ bd1,
    const float* __restrict__ Wd2, const float* __restrict__ bd2,
    const float* __restrict__ Wd3, const float* __restrict__ bd3,
    const float* __restrict__ Wr1, const float* __restrict__ br1,
    const float* __restrict__ Wr2, const float* __restrict__ br2,
    const float* __restrict__ Wr3, const float* __restrict__ br3,
    float4* __restrict__ ws4, int* __restrict__ start)
{
    const int lane = threadIdx.x & 63;
    const int wv   = (blockIdx.x * blockDim.x + threadIdx.x) >> 6;
    const int q    = lane >> 4;
    const int n    = lane & 15;
    const int qn   = n >> 2, rn = n & 3;
    const int rt   = n & 3;          // L3 row type: 0=sigma, 1..3=rgb

    // ---- A1: rows pi(t,n); W1 j-rows + bias replicated in all quads ----
    bf8 a1d[4], a1r[4];
    #pragma unroll
    for (int t = 0; t < 4; ++t) {
        const int row = 8*qn + 4*(t&1) + rn + 32*(t>>1);
        BF8U fd, fr;
        fd.u[0] = pk2(Wd1[row],       Wd1[HID+row]);
        fd.u[1] = pk2(Wd1[2*HID+row], bd1[row]);
        fd.u[2] = 0u; fd.u[3] = 0u;
        fr.u[0] = pk2(Wr1[row],       Wr1[HID+row]);
        fr.u[1] = pk2(Wr1[2*HID+row], br1[row]);
        fr.u[2] = 0u; fr.u[3] = 0u;
        a1d[t] = fd.v; a1r[t] = fr.v;
    }

    // ---- A2: rows pi(t,n), k = 8q + j + 32s ----
    bf8 a2d[4][2], a2r[4][2];
    #pragma unroll
    for (int t = 0; t < 4; ++t) {
        const int row = 8*qn + 4*(t&1) + rn + 32*(t>>1);
        #pragma unroll
        for (int s = 0; s < 2; ++s) {
            BF8U fd, fr;
            #pragma unroll
            for (int dw = 0; dw < 4; ++dw) {
                const int k = 8*q + 2*dw + 32*s;
                fd.u[dw] = pk2(Wd2[k*HID+row], Wd2[(k+1)*HID+row]);
                fr.u[dw] = pk2(Wr2[k*HID+row], Wr2[(k+1)*HID+row]);
            }
            a2d[t][s] = fd.v; a2r[t][s] = fr.v;
        }
    }

    // ---- A3 row-duplicated: row m -> type m&3 (0=Wd3 sigma, 1..3=Wr3 rgb) ----
    bf8 a3[4];
    #pragma unroll
    for (int s = 0; s < 4; ++s) {
        BF8U f;
        #pragma unroll
        for (int dw = 0; dw < 4; ++dw) {
            const int kg = 32*s + 8*q + 2*dw;
            float va = 0.f, vb = 0.f;
            if (rt == 0 && s < 2) { va = Wd3[kg]; vb = Wd3[kg+1]; }
            else if (rt >= 1 && s >= 2) {
                va = Wr3[(kg-64)*3 + (rt-1)];
                vb = Wr3[(kg-63)*3 + (rt-1)];
            }
            f.u[dw] = pk2(va, vb);
        }
        a3[s] = f.v;
    }

    // ---- accumulator biases ----
    f4 bias2d[4], bias2r[4];
    #pragma unroll
    for (int t = 0; t < 4; ++t) {
        #pragma unroll
        for (int rr = 0; rr < 4; ++rr) {
            const int row = 8*q + 4*(t&1) + rr + 32*(t>>1);
            bias2d[t][rr] = bd2[row];
            bias2r[t][rr] = br2[row];
        }
    }
    f4 bias3;   // duplicated rows: every quad gets (bd3, br3[0..2])
    #pragma unroll
    for (int rr = 0; rr < 4; ++rr)
        bias3[rr] = (rr == 0) ? bd3[0] : br3[rr-1];

    const int base0 = wv * (ITERS * 64);

    #pragma unroll 1
    for (int it = 0; it < ITERS; ++it) {
        const int base = base0 + it * 64;
        const int smp  = base + lane;

        const float ts = t_starts[smp], te = t_ends[smp];
        const int   ri = ray_idx[smp];
        const float mid = 0.5f*(ts+te), dt = te - ts;
        const float px = rays_o[3*ri+0] + rays_d[3*ri+0]*mid;
        const float py = rays_o[3*ri+1] + rays_d[3*ri+1]*mid;
        const float pz = rays_o[3*ri+2] + rays_d[3*ri+2]*mid;
        const unsigned p01 = pk2(px, py);
        const unsigned p23 = pk2(pz, 1.0f);

        // segment boundaries (replaces seg_starts kernel)
        int rp = __shfl_up(ri, 1, 64);
        if (lane == 0) rp = (smp == 0) ? -1 : ray_idx[smp-1];
        for (int rr = rp + 1; rr <= ri; ++rr) start[rr] = smp;
        if (smp == N_SAMP - 1)
            for (int rr = ri + 1; rr <= N_RAYS; ++rr) start[rr] = N_SAMP;

        f4 mine = {0.f, 0.f, 0.f, 0.f};

        #pragma unroll
        for (int u = 0; u < 4; ++u) {
            BF8U xb;
            xb.u[0] = (q == u) ? p01 : 0u;
            xb.u[1] = (q == u) ? p23 : 0u;
            xb.u[2] = 0u; xb.u[3] = 0u;

            const f4 zero = {0.f, 0.f, 0.f, 0.f};
            f4 d1d[4], d1r[4];
            #pragma unroll
            for (int t = 0; t < 4; ++t) {
                d1d[t] = mfma16(a1d[t], xb.v, zero);
                d1r[t] = mfma16(a1r[t], xb.v, zero);
            }

            bf8 b2d[2], b2r[2];
            #pragma unroll
            for (int s = 0; s < 2; ++s) {
                BF8U pd, pr;
                pd.u[0] = pk2r(d1d[2*s][0],   d1d[2*s][1]);
                pd.u[1] = pk2r(d1d[2*s][2],   d1d[2*s][3]);
                pd.u[2] = pk2r(d1d[2*s+1][0], d1d[2*s+1][1]);
                pd.u[3] = pk2r(d1d[2*s+1][2], d1d[2*s+1][3]);
                pr.u[0] = pk2r(d1r[2*s][0],   d1r[2*s][1]);
                pr.u[1] = pk2r(d1r[2*s][2],   d1r[2*s][3]);
                pr.u[2] = pk2r(d1r[2*s+1][0], d1r[2*s+1][1]);
                pr.u[3] = pk2r(d1r[2*s+1][2], d1r[2*s+1][3]);
                b2d[s] = pd.v; b2r[s] = pr.v;
            }

            f4 d2d[4], d2r[4];
            #pragma unroll
            for (int t = 0; t < 4; ++t) {
                f4 ad = bias2d[t];
                ad = mfma16(a2d[t][0], b2d[0], ad);
                ad = mfma16(a2d[t][1], b2d[1], ad);
                d2d[t] = ad;
                f4 ar = bias2r[t];
                ar = mfma16(a2r[t][0], b2r[0], ar);
                ar = mfma16(a2r[t][1], b2r[1], ar);
                d2r[t] = ar;
            }

            bf8 b3[4];
            #pragma unroll
            for (int s = 0; s < 2; ++s) {
                BF8U pd, pr;
                pd.u[0] = pk2r(d2d[2*s][0],   d2d[2*s][1]);
                pd.u[1] = pk2r(d2d[2*s][2],   d2d[2*s][3]);
                pd.u[2] = pk2r(d2d[2*s+1][0], d2d[2*s+1][1]);
                pd.u[3] = pk2r(d2d[2*s+1][2], d2d[2*s+1][3]);
                pr.u[0] = pk2r(d2r[2*s][0],   d2r[2*s][1]);
                pr.u[1] = pk2r(d2r[2*s][2],   d2r[2*s][3]);
                pr.u[2] = pk2r(d2r[2*s+1][0], d2r[2*s+1][1]);
                pr.u[3] = pk2r(d2r[2*s+1][2], d2r[2*s+1][3]);
                b3[s] = pd.v; b3[s+2] = pr.v;
            }

            f4 c3 = bias3;
            #pragma unroll
            for (int s = 0; s < 4; ++s) c3 = mfma16(a3[s], b3[s], c3);

            if (q == u) mine = c3;   // lane's own sample's (sigma,r,g,b)
        }

        // full-width epilogue: every lane handles its OWN sample (own dt)
        const float sg = mine[0];
        const float sp = fmaxf(sg, 0.f) + __logf(1.f + __expf(-fabsf(sg)));
        const float sd = sp * dt;
        const float r0 = __builtin_amdgcn_rcpf(1.f + __expf(-mine[1]));
        const float g0 = __builtin_amdgcn_rcpf(1.f + __expf(-mine[2]));
        const float b0 = __builtin_amdgcn_rcpf(1.f + __expf(-mine[3]));
        ws4[smp] = make_float4(r0, g0, b0, sd);
    }
}

// ---------------------------------------------------------------------------
// Pass B: TWO rays per wave (32 lanes each). Telescoping weights
// w = exp(-excl) - exp(-incl); per-chunk closed-form opacity (no reduce).
// start[] values clamped: rocprof dispatch-replay can hand this kernel a
// re-poisoned (0xAA) workspace -> unguarded loop ran 41ms in profiling.
// ---------------------------------------------------------------------------
__global__ __launch_bounds__(256) void pass_b(
    const float* __restrict__ t_starts, const float* __restrict__ t_ends,
    const float4* __restrict__ ws4, const int* __restrict__ start,
    float* __restrict__ out)
{
    const int lane = threadIdx.x & 63;
    const int wv   = (blockIdx.x * blockDim.x + threadIdx.x) >> 6;
    const int half = lane >> 5;
    const int l32  = lane & 31;
    const int r    = 2*wv + half;
    if (r >= N_RAYS) return;

    int s0 = start[r], s1 = start[r+1];
    s0 = min(max(s0, 0), N_SAMP);
    s1 = min(max(s1, s0), N_SAMP);

    float cum = 0.f, opac = 0.f, dist = 0.f, c0 = 0.f, c1 = 0.f, c2 = 0.f;

    for (int base = s0; base < s1; base += 32) {
        int s = base + l32;
        bool ok = s < s1;
        float4 v  = ok ? ws4[s] : make_float4(0.f, 0.f, 0.f, 0.f);
        float mid = ok ? 0.5f*(t_starts[s] + t_ends[s]) : 0.f;
        float sd  = v.w;

        float x = sd;                       // inclusive scan over 32 lanes
        #pragma unroll
        for (int off = 1; off < 32; off <<= 1) {
            float y = __shfl_up(x, off, 32);
            if (l32 >= off) x += y;
        }
        float incl = cum + x;
        float excl = incl - sd;
        float w = __expf(-excl) - __expf(-incl);   // trans*alpha, telescoped
        dist += w*mid; c0 += w*v.x; c1 += w*v.y; c2 += w*v.z;

        float tot = __shfl(x, 31, 32);
        opac += __expf(-cum) - __expf(-(cum + tot));  // uniform across lanes
        cum  += tot;
    }

    #pragma unroll
    for (int off = 16; off > 0; off >>= 1) {
        dist += __shfl_xor(dist, off, 32);
        c0   += __shfl_xor(c0,   off, 32);
        c1   += __shfl_xor(c1,   off, 32);
        c2   += __shfl_xor(c2,   off, 32);
    }

    if (l32 == 0) {
        float rest = 1.f - opac;
        out[r*3 + 0] = c0 + 0.5f * rest;
        out[r*3 + 1] = c1 + 0.5f * rest;
        out[r*3 + 2] = c2 + 0.5f * rest;
        out[3*N_RAYS + r] = dist + 5.f * rest;
        out[4*N_RAYS + r] = opac;
    }
}

extern "C" void kernel_launch(void* const* d_in, const int* in_sizes, int n_in,
                              void* d_out, int out_size, void* d_ws, size_t ws_size,
                              hipStream_t stream) {
    const float* rays_o   = (const float*)d_in[0];
    const float* rays_d   = (const float*)d_in[1];
    const float* t_starts = (const float*)d_in[2];
    const float* t_ends   = (const float*)d_in[3];
    const int*   ray_idx  = (const int*)  d_in[4];
    const float* Wd1 = (const float*)d_in[5];  const float* bd1 = (const float*)d_in[6];
    const float* Wd2 = (const float*)d_in[7];  const float* bd2 = (const float*)d_in[8];
    const float* Wd3 = (const float*)d_in[9];  const float* bd3 = (const float*)d_in[10];
    const float* Wr1 = (const float*)d_in[11]; const float* br1 = (const float*)d_in[12];
    const float* Wr2 = (const float*)d_in[13]; const float* br2 = (const float*)d_in[14];
    const float* Wr3 = (const float*)d_in[15]; const float* br3 = (const float*)d_in[16];

    float4* ws4   = (float4*)d_ws;                                // 16 MB
    int*    start = (int*)((char*)d_ws + (size_t)N_SAMP * 16);    // +~128 KB
    float*  out   = (float*)d_out;

    hipLaunchKernelGGL(pass_a, dim3(BLK_A), dim3(256), 0, stream,
                       rays_o, rays_d, t_starts, t_ends, ray_idx,
                       Wd1, bd1, Wd2, bd2, Wd3, bd3,
                       Wr1, br1, Wr2, br2, Wr3, br3, ws4, start);

    // 2 rays per wave -> 16384 waves -> 4096 blocks of 256
    hipLaunchKernelGGL(pass_b, dim3((N_RAYS/2 * 64) / 256), dim3(256), 0, stream,
                       t_starts, t_ends, ws4, start, out);
}

// Round 7
// 147.862 us; speedup vs baseline: 1.1058x; 1.1058x over previous
//
#include <hip/hip_runtime.h>
#include <hip/hip_bf16.h>
#include <math.h>

#define N_RAYS   32768
#define N_SAMP   1048576
#define HID      64
#define ITERS    4
#define BLK_HALF 1024               // per net: 1024 blk * 4 waves * 4 iters * 64 = 1,048,576
#define BLK_A    (2*BLK_HALF)       // blocks [0,1024): density, [1024,2048): rgb

typedef short bf8 __attribute__((ext_vector_type(8)));   // 8 x bf16 bits
typedef float f4  __attribute__((ext_vector_type(4)));

union BF8U { bf8 v; unsigned u[4]; };

// f32->bf16 pair pack via the C++ cast: the compiler fuses cast pairs into
// v_cvt_pk_bf16_f32 on gfx950. DO NOT replace with manual bit-twiddled RNE —
// R6 measured it 45% SLOWER (defeats the fusion; VALU-busy cyc 79k->101k).
static __device__ __forceinline__ unsigned bfbits(float x) {
    union { __bf16 h; unsigned short s; } c; c.h = (__bf16)x; return (unsigned)c.s;
}
static __device__ __forceinline__ unsigned pk2(float a, float b) {
#if __has_builtin(__builtin_amdgcn_cvt_pk_bf16_f32)
    return __builtin_bit_cast(unsigned, __builtin_amdgcn_cvt_pk_bf16_f32(a, b));
#else
    return bfbits(a) | (bfbits(b) << 16);
#endif
}
static __device__ __forceinline__ unsigned pk2r(float a, float b) {
    return pk2(fmaxf(a, 0.f), fmaxf(b, 0.f));
}
static __device__ __forceinline__ f4 mfma16(bf8 a, bf8 b, f4 c) {
    return __builtin_amdgcn_mfma_f32_16x16x32_bf16(a, b, c, 0, 0, 0);
}

// ---------------------------------------------------------------------------
// Pass A, SPLIT BY NET: each block runs ONE of the two MLPs for its samples.
// Rationale (R5/R6 evidence): combined-net resident fragments (~230 regs)
// exceeded the 108 arch VGPRs -> AGPR spill traffic ~1500 v_accvgpr moves per
// wave-iter = the hidden 55% VALUBusy. Split halves the footprint.
// BUG FIX vs R2-R6: A1 k-slots are now filled in EVERY quad (tile u's B1 is
// nonzero at k=8u..8u+3, so A1 must replicate W1 across all quads' k-slots;
// the old q==0-only fill made d1==0 for tiles u>=1 — masked by zero biases).
// ---------------------------------------------------------------------------
__global__ __launch_bounds__(256, 2) void pass_a(
    const float* __restrict__ rays_o, const float* __restrict__ rays_d,
    const float* __restrict__ t_starts, const float* __restrict__ t_ends,
    const int*   __restrict__ ray_idx,
    const float* __restrict__ Wd1, const float* __restrict__ bd1,
    const float* __restrict__ Wd2, const float* __restrict__ bd2,
    const float* __restrict__ Wd3, const float* __restrict__ bd3,
    const float* __restrict__ Wr1, const float* __restrict__ br1,
    const float* __restrict__ Wr2, const float* __restrict__ br2,
    const float* __restrict__ Wr3, const float* __restrict__ br3,
    float* __restrict__ ws_sd, float* __restrict__ ws_r,
    float* __restrict__ ws_g,  float* __restrict__ ws_b,
    int* __restrict__ start)
{
    const bool is_rgb = blockIdx.x >= BLK_HALF;
    const int  blk    = is_rgb ? (blockIdx.x - BLK_HALF) : blockIdx.x;
    const int  lane   = threadIdx.x & 63;
    const int  wv     = ((blk << 8) + threadIdx.x) >> 6;   // 0..4095 per net
    const int  q      = lane >> 4;
    const int  n      = lane & 15;
    const int  qn     = n >> 2, rn = n & 3;
    const int  rt     = n & 3;

    const float* W1 = is_rgb ? Wr1 : Wd1;  const float* b1 = is_rgb ? br1 : bd1;
    const float* W2 = is_rgb ? Wr2 : Wd2;  const float* b2 = is_rgb ? br2 : bd2;
    const float* W3 = is_rgb ? Wr3 : Wd3;  const float* b3 = is_rgb ? br3 : bd3;
    const int    nc = is_rgb ? 3 : 1;
    const int    ch = is_rgb ? (rt < 3 ? rt : 2) : 0;   // L3 row type -> out channel

    // ---- A1: rows pi(t,n); W1 j-rows + bias replicated in ALL quads' k-slots ----
    bf8 a1[4];
    #pragma unroll
    for (int t = 0; t < 4; ++t) {
        const int row = 8*qn + 4*(t&1) + rn + 32*(t>>1);
        BF8U f;
        f.u[0] = pk2(W1[row],       W1[HID+row]);
        f.u[1] = pk2(W1[2*HID+row], b1[row]);
        f.u[2] = 0u; f.u[3] = 0u;
        a1[t] = f.v;
    }

    // ---- A2: rows pi(t,n), k = 8q + 2dw + 32s ----
    bf8 a2[4][2];
    #pragma unroll
    for (int t = 0; t < 4; ++t) {
        const int row = 8*qn + 4*(t&1) + rn + 32*(t>>1);
        #pragma unroll
        for (int s = 0; s < 2; ++s) {
            BF8U f;
            #pragma unroll
            for (int dw = 0; dw < 4; ++dw) {
                const int k = 8*q + 2*dw + 32*s;
                f.u[dw] = pk2(W2[k*HID+row], W2[(k+1)*HID+row]);
            }
            a2[t][s] = f.v;
        }
    }

    // ---- A3 row-duplicated: row m -> channel ch(m&3); K=64 over 2 frags ----
    bf8 a3[2];
    #pragma unroll
    for (int s = 0; s < 2; ++s) {
        BF8U f;
        #pragma unroll
        for (int dw = 0; dw < 4; ++dw) {
            const int kg = 32*s + 8*q + 2*dw;
            f.u[dw] = pk2(W3[kg*nc + ch], W3[(kg+1)*nc + ch]);
        }
        a3[s] = f.v;
    }

    // ---- accumulator biases ----
    f4 bias2[4];
    #pragma unroll
    for (int t = 0; t < 4; ++t) {
        #pragma unroll
        for (int rr = 0; rr < 4; ++rr) {
            const int row = 8*q + 4*(t&1) + rr + 32*(t>>1);
            bias2[t][rr] = b2[row];
        }
    }
    f4 bias3;
    #pragma unroll
    for (int rr = 0; rr < 4; ++rr)
        bias3[rr] = is_rgb ? b3[rr < 3 ? rr : 2] : b3[0];

    const int base0 = wv * (ITERS * 64);

    #pragma unroll 1
    for (int it = 0; it < ITERS; ++it) {
        const int base = base0 + it * 64;
        const int smp  = base + lane;

        const float ts = t_starts[smp], te = t_ends[smp];
        const int   ri = ray_idx[smp];
        const float mid = 0.5f*(ts+te), dt = te - ts;
        const float px = rays_o[3*ri+0] + rays_d[3*ri+0]*mid;
        const float py = rays_o[3*ri+1] + rays_d[3*ri+1]*mid;
        const float pz = rays_o[3*ri+2] + rays_d[3*ri+2]*mid;
        const unsigned p01 = pk2(px, py);
        const unsigned p23 = pk2(pz, 1.0f);

        if (!is_rgb) {
            // segment boundaries (density half only)
            int rp = __shfl_up(ri, 1, 64);
            if (lane == 0) rp = (smp == 0) ? -1 : ray_idx[smp-1];
            for (int rr = rp + 1; rr <= ri; ++rr) start[rr] = smp;
            if (smp == N_SAMP - 1)
                for (int rr = ri + 1; rr <= N_RAYS; ++rr) start[rr] = N_SAMP;
        }

        f4 mine = {0.f, 0.f, 0.f, 0.f};

        #pragma unroll
        for (int u = 0; u < 4; ++u) {
            BF8U xb;
            xb.u[0] = (q == u) ? p01 : 0u;
            xb.u[1] = (q == u) ? p23 : 0u;
            xb.u[2] = 0u; xb.u[3] = 0u;

            const f4 zero = {0.f, 0.f, 0.f, 0.f};
            f4 d1[4];
            #pragma unroll
            for (int t = 0; t < 4; ++t) d1[t] = mfma16(a1[t], xb.v, zero);

            bf8 bf2[2];
            #pragma unroll
            for (int s = 0; s < 2; ++s) {
                BF8U p;
                p.u[0] = pk2r(d1[2*s][0],   d1[2*s][1]);
                p.u[1] = pk2r(d1[2*s][2],   d1[2*s][3]);
                p.u[2] = pk2r(d1[2*s+1][0], d1[2*s+1][1]);
                p.u[3] = pk2r(d1[2*s+1][2], d1[2*s+1][3]);
                bf2[s] = p.v;
            }

            f4 d2[4];
            #pragma unroll
            for (int t = 0; t < 4; ++t) {
                f4 a = bias2[t];
                a = mfma16(a2[t][0], bf2[0], a);
                a = mfma16(a2[t][1], bf2[1], a);
                d2[t] = a;
            }

            bf8 bf3[2];
            #pragma unroll
            for (int s = 0; s < 2; ++s) {
                BF8U p;
                p.u[0] = pk2r(d2[2*s][0],   d2[2*s][1]);
                p.u[1] = pk2r(d2[2*s][2],   d2[2*s][3]);
                p.u[2] = pk2r(d2[2*s+1][0], d2[2*s+1][1]);
                p.u[3] = pk2r(d2[2*s+1][2], d2[2*s+1][3]);
                bf3[s] = p.v;
            }

            f4 c3 = bias3;
            c3 = mfma16(a3[0], bf3[0], c3);
            c3 = mfma16(a3[1], bf3[1], c3);

            if (q == u) mine = c3;   // lane's own sample's outputs
        }

        // full-width epilogue: every lane handles its OWN sample
        if (!is_rgb) {
            const float sg = mine[0];
            const float sp = fmaxf(sg, 0.f) + __logf(1.f + __expf(-fabsf(sg)));
            ws_sd[smp] = sp * dt;
        } else {
            ws_r[smp] = __builtin_amdgcn_rcpf(1.f + __expf(-mine[0]));
            ws_g[smp] = __builtin_amdgcn_rcpf(1.f + __expf(-mine[1]));
            ws_b[smp] = __builtin_amdgcn_rcpf(1.f + __expf(-mine[2]));
        }
    }
}

// ---------------------------------------------------------------------------
// Pass B: TWO rays per wave (32 lanes each). Telescoping weights
// w = exp(-excl) - exp(-incl); per-chunk closed-form opacity (no reduce).
// start[] clamped: rocprof dispatch-replay can hand this kernel re-poisoned
// (0xAA) workspace -> unguarded loop ran 41ms under profiling (R4).
// ---------------------------------------------------------------------------
__global__ __launch_bounds__(256) void pass_b(
    const float* __restrict__ t_starts, const float* __restrict__ t_ends,
    const float* __restrict__ ws_sd, const float* __restrict__ ws_r,
    const float* __restrict__ ws_g,  const float* __restrict__ ws_b,
    const int* __restrict__ start, float* __restrict__ out)
{
    const int lane = threadIdx.x & 63;
    const int wv   = (blockIdx.x * blockDim.x + threadIdx.x) >> 6;
    const int half = lane >> 5;
    const int l32  = lane & 31;
    const int r    = 2*wv + half;
    if (r >= N_RAYS) return;

    int s0 = start[r], s1 = start[r+1];
    s0 = min(max(s0, 0), N_SAMP);
    s1 = min(max(s1, s0), N_SAMP);

    float cum = 0.f, opac = 0.f, dist = 0.f, c0 = 0.f, c1 = 0.f, c2 = 0.f;

    for (int base = s0; base < s1; base += 32) {
        int s = base + l32;
        bool ok = s < s1;
        float sd  = ok ? ws_sd[s] : 0.f;
        float vr  = ok ? ws_r[s]  : 0.f;
        float vg  = ok ? ws_g[s]  : 0.f;
        float vb  = ok ? ws_b[s]  : 0.f;
        float mid = ok ? 0.5f*(t_starts[s] + t_ends[s]) : 0.f;

        float x = sd;                       // inclusive scan over 32 lanes
        #pragma unroll
        for (int off = 1; off < 32; off <<= 1) {
            float y = __shfl_up(x, off, 32);
            if (l32 >= off) x += y;
        }
        float incl = cum + x;
        float excl = incl - sd;
        float w = __expf(-excl) - __expf(-incl);   // trans*alpha, telescoped
        dist += w*mid; c0 += w*vr; c1 += w*vg; c2 += w*vb;

        float tot = __shfl(x, 31, 32);
        opac += __expf(-cum) - __expf(-(cum + tot));  // uniform across lanes
        cum  += tot;
    }

    #pragma unroll
    for (int off = 16; off > 0; off >>= 1) {
        dist += __shfl_xor(dist, off, 32);
        c0   += __shfl_xor(c0,   off, 32);
        c1   += __shfl_xor(c1,   off, 32);
        c2   += __shfl_xor(c2,   off, 32);
    }

    if (l32 == 0) {
        float rest = 1.f - opac;
        out[r*3 + 0] = c0 + 0.5f * rest;
        out[r*3 + 1] = c1 + 0.5f * rest;
        out[r*3 + 2] = c2 + 0.5f * rest;
        out[3*N_RAYS + r] = dist + 5.f * rest;
        out[4*N_RAYS + r] = opac;
    }
}

extern "C" void kernel_launch(void* const* d_in, const int* in_sizes, int n_in,
                              void* d_out, int out_size, void* d_ws, size_t ws_size,
                              hipStream_t stream) {
    const float* rays_o   = (const float*)d_in[0];
    const float* rays_d   = (const float*)d_in[1];
    const float* t_starts = (const float*)d_in[2];
    const float* t_ends   = (const float*)d_in[3];
    const int*   ray_idx  = (const int*)  d_in[4];
    const float* Wd1 = (const float*)d_in[5];  const float* bd1 = (const float*)d_in[6];
    const float* Wd2 = (const float*)d_in[7];  const float* bd2 = (const float*)d_in[8];
    const float* Wd3 = (const float*)d_in[9];  const float* bd3 = (const float*)d_in[10];
    const float* Wr1 = (const float*)d_in[11]; const float* br1 = (const float*)d_in[12];
    const float* Wr2 = (const float*)d_in[13]; const float* br2 = (const float*)d_in[14];
    const float* Wr3 = (const float*)d_in[15]; const float* br3 = (const float*)d_in[16];

    float* ws_sd = (float*)d_ws;                       // SoA planes, 4 MB each
    float* ws_r  = ws_sd + N_SAMP;
    float* ws_g  = ws_r  + N_SAMP;
    float* ws_b  = ws_g  + N_SAMP;
    int*   start = (int*)(ws_b + N_SAMP);              // +128 KB
    float* out   = (float*)d_out;

    hipLaunchKernelGGL(pass_a, dim3(BLK_A), dim3(256), 0, stream,
                       rays_o, rays_d, t_starts, t_ends, ray_idx,
                       Wd1, bd1, Wd2, bd2, Wd3, bd3,
                       Wr1, br1, Wr2, br2, Wr3, br3,
                       ws_sd, ws_r, ws_g, ws_b, start);

    // 2 rays per wave -> 16384 waves -> 4096 blocks of 256
    hipLaunchKernelGGL(pass_b, dim3((N_RAYS/2 * 64) / 256), dim3(256), 0, stream,
                       t_starts, t_ends, ws_sd, ws_r, ws_g, ws_b, start, out);
}